// Round 9
// baseline (524.542 us; speedup 1.0000x reference)
//
#include <hip/hip_runtime.h>

#define N_NODES 100000
#define N_EDGES 1600000
#define NGRAPH 64
#define NBIN 391        // ceil(100000/256) bins of 256 nodes (dst>>8)
#define EPB 2560        // edges per binning block (multiple of 512)
#define NBLK 625        // 625*2560 = 1.6M
#define CAPB 6144       // staging per-bin capacity (unpadded; avg 4092, +32 sigma)
#define CAPP 7168       // padded colidx per-bin stride (avg 6144 w/ pad-16, ~+8 sigma)
#define SETUPBLK 1600   // k_setup grid (covers wbuf 51100 and x-convert stride)

typedef short s8v __attribute__((ext_vector_type(8)));
typedef float f4v __attribute__((ext_vector_type(4)));
typedef float f2v __attribute__((ext_vector_type(2)));

__device__ __forceinline__ float bflo(unsigned u) { return __uint_as_float(u << 16); }
__device__ __forceinline__ float bfhi(unsigned u) { return __uint_as_float(u & 0xffff0000u); }
__device__ __forceinline__ unsigned short f2bf(float f) {
    unsigned u = __float_as_uint(f);
    u += 0x7fffu + ((u >> 16) & 1u);
    return (unsigned short)(u >> 16);
}
__device__ __forceinline__ float bf2f(unsigned short h) { return __uint_as_float(((unsigned)h) << 16); }
__device__ __forceinline__ unsigned pk(float lo, float hi) {
    return (unsigned)f2bf(lo) | ((unsigned)f2bf(hi) << 16);
}
__device__ __forceinline__ float ldv(const void* p, int i, int f32) {
    return f32 ? ((const float*)p)[i] : bf2f(((const unsigned short*)p)[i]);
}
__device__ __forceinline__ f2v up2(unsigned u) {
    f2v t; t.x = bflo(u); t.y = bfhi(u); return t;
}

// ------- setup + cvt_w + x-convert merged: every block detects dtype locally ------
__global__ __launch_bounds__(256) void k_setup(const unsigned short* __restrict__ x,
                                               const int* __restrict__ ei,
                                               const int* __restrict__ batch,
                                               int* __restrict__ flags,
                                               int* __restrict__ binCur,
                                               int* __restrict__ gstart,
                                               float* __restrict__ pbuf,
                                               float* __restrict__ wbuf,
                                               unsigned* __restrict__ xcvt,
                                               float* __restrict__ pgsum,
                                               const void* w0, const void* w1,
                                               const void* w2, const void* w3,
                                               const void* b0, const void* bn0g, const void* bn0b,
                                               const void* b1, const void* bn1g, const void* bn1b,
                                               const void* b2, const void* bn2g, const void* bn2b,
                                               const void* b3) {
    __shared__ int cnt[3];
    int tid = threadIdx.x, bid = blockIdx.x;
    if (tid < 3) cnt[tid] = 0;
    __syncthreads();
    unsigned short h = x[tid * 37];
    int e = (h >> 7) & 0xFF;
    if (e >= 100 && e <= 150) atomicAdd(&cnt[0], 1);
    if (bid == 0) {
        if (ei[2 * (tid * 5000) + 1] == 0) atomicAdd(&cnt[1], 1);
        if (batch[2 * (tid * 193) + 1] == 0) atomicAdd(&cnt[2], 1);
    }
    __syncthreads();
    int f = (cnt[0] == 256) ? 0 : 1;
    // weight conversion slice (blocks 0..199)
    int i = bid * 256 + tid;
    if (i < 25600) wbuf[i] = ldv(w0, i, f);
    else if (i < 45600) wbuf[i] = ldv(w1, i - 25600, f);
    else if (i < 50600) wbuf[i] = ldv(w2, i - 45600, f);
    else if (i < 51100) wbuf[i] = ldv(w3, i - 50600, f);
    // f32 inputs: convert x -> xcvt (bf16), grid-stride
    if (f) {
        for (int id = bid * 256 + tid; id < N_NODES * 64; id += SETUPBLK * 256) {
            float2 u = ((const float2*)x)[id];
            xcvt[id] = pk(u.x, u.y);
        }
    }
    if (bid != 0) return;
    int b64 = (cnt[2] == 256) ? 1 : 0;
    if (tid == 0) {
        flags[0] = f;
        flags[1] = (cnt[1] == 256) ? 1 : 0;
        flags[2] = b64;
    }
    for (int k = tid; k < NBIN; k += 256) binCur[k] = 0;
    for (int k = tid; k < NGRAPH * 128; k += 256) pgsum[k] = 0.f;
    if (tid <= NGRAPH) {
        int g = tid, lo = 0, hi = N_NODES;
        while (lo < hi) {
            int mid = (lo + hi) >> 1;
            int v = b64 ? batch[2 * mid] : batch[mid];
            if (v < g) lo = mid + 1;
            else hi = mid;
        }
        gstart[g] = lo;
    }
    const float invs = rsqrtf(1.0f + 1e-5f);
    if (tid < 200) {
        float a = ldv(bn0g, tid, f) * invs;
        pbuf[tid] = a;
        pbuf[200 + tid] = ldv(b0, tid, f) * a + ldv(bn0b, tid, f);
    }
    if (tid < 100) {
        float a = ldv(bn1g, tid, f) * invs;
        pbuf[400 + tid] = a;
        pbuf[500 + tid] = ldv(b1, tid, f) * a + ldv(bn1b, tid, f);
    }
    if (tid < 50) {
        float a = ldv(bn2g, tid, f) * invs;
        pbuf[600 + tid] = a;
        pbuf[650 + tid] = ldv(b2, tid, f) * a + ldv(bn2b, tid, f);
    }
    if (tid < 10) pbuf[700 + tid] = ldv(b3, tid, f);
}

// ---------------- LEAN binfill: histogram -> reserve -> direct scatter ----------
__global__ __launch_bounds__(256) void k_binfill(const int* __restrict__ ei,
                                                 int* __restrict__ binCur,
                                                 unsigned* __restrict__ staging,
                                                 const int* __restrict__ flags) {
    __shared__ int cnt[NBIN];
    __shared__ int basg[NBIN];
    __shared__ int dbuf[EPB];
    int tid = threadIdx.x;
    int i64 = flags[1];
    int base = blockIdx.x * EPB;
    for (int i = tid; i < NBIN; i += 256) cnt[i] = 0;
    __syncthreads();
    // pass 1: dst (cached in LDS), histogram
    #pragma unroll
    for (int k = 0; k < EPB / 512; ++k) {
        int e = base + k * 512 + tid * 2;
        int d0, d1;
        if (i64) {
            uint4 vd = *(const uint4*)(ei + 2 * (size_t)(N_EDGES + e));
            d0 = (int)vd.x; d1 = (int)vd.z;
        } else {
            int2 vd = *(const int2*)(ei + (size_t)N_EDGES + e);
            d0 = vd.x; d1 = vd.y;
        }
        int l = k * 512 + tid * 2;
        dbuf[l] = d0; dbuf[l + 1] = d1;
        if ((unsigned)d0 < N_NODES) atomicAdd(&cnt[d0 >> 8], 1);
        if ((unsigned)d1 < N_NODES) atomicAdd(&cnt[d1 >> 8], 1);
    }
    __syncthreads();
    // reserve a contiguous run per bin; reuse cnt as scatter cursor
    for (int i = tid; i < NBIN; i += 256) {
        int c = cnt[i];
        basg[i] = i * CAPB + (c ? atomicAdd(&binCur[i], c) : 0);
        cnt[i] = 0;
    }
    __syncthreads();
    // pass 2: src from global (L2-hot lines), direct scatter into reserved runs
    #pragma unroll
    for (int k = 0; k < EPB / 512; ++k) {
        int e = base + k * 512 + tid * 2;
        int s0, s1;
        if (i64) {
            uint4 vs = *(const uint4*)(ei + 2 * (size_t)e);
            s0 = (int)vs.x; s1 = (int)vs.z;
        } else {
            int2 vs = *(const int2*)(ei + (size_t)e);
            s0 = vs.x; s1 = vs.y;
        }
        int l = k * 512 + tid * 2;
        #pragma unroll
        for (int hh = 0; hh < 2; ++hh) {
            int d = dbuf[l + hh];
            int s = hh ? s1 : s0;
            if ((unsigned)d < N_NODES) {
                s = min(max(s, 0), N_NODES - 1);
                int b = d >> 8;
                int p = atomicAdd(&cnt[b], 1);
                int pos = basg[b] + p;
                if (pos < (b + 1) * CAPB)
                    staging[pos] = ((unsigned)(d & 255) << 20) | (unsigned)s;
            }
        }
    }
}

// per-bin sub-CSR -> rse(int2) + dinv + PADDED colidx (pad idx = N_NODES).
// shfl-scan (1 barrier) + gap-only pad init. Block 0 zeroes pad rows + dinv[N].
__global__ __launch_bounds__(256) void k_csr(const unsigned* __restrict__ staging,
                                             const int* __restrict__ binCur,
                                             int2* __restrict__ rse,
                                             float* __restrict__ dinv,
                                             int* __restrict__ colidx,
                                             unsigned* __restrict__ padA,
                                             unsigned* __restrict__ padB) {
    __shared__ int deg[256];
    __shared__ int cur[256];
    __shared__ int wsum[4];
    __shared__ int colbuf[CAPP];
    int b = blockIdx.x, tid = threadIdx.x;
    int lane = tid & 63, wv = tid >> 6;
    int n0 = b << 8;
    int nend = min(256, N_NODES - n0);
    int runStart = b * CAPB;
    int outStart = b * CAPP;
    int runLen = min(binCur[b], CAPB);
    deg[tid] = 0;
    __syncthreads();
    for (int i = tid; i < runLen; i += 256)
        atomicAdd(&deg[staging[runStart + i] >> 20], 1);
    __syncthreads();
    int myDeg = deg[tid];
    int pdeg = (myDeg + 15) & ~15;   // pad each node's list to x16
    // per-wave inclusive shfl scan of pdeg, then cross-wave prefix
    int v = pdeg;
    #pragma unroll
    for (int off = 1; off < 64; off <<= 1) {
        int n = __shfl_up(v, off, 64);
        if (lane >= off) v += n;
    }
    if (lane == 63) wsum[wv] = v;
    __syncthreads();
    int prefix = 0;
    #pragma unroll
    for (int w = 0; w < 4; ++w) prefix += (w < wv) ? wsum[w] : 0;
    int incl = v + prefix;
    int lrs = incl - pdeg;
    if (tid < nend) {
        rse[n0 + tid] = make_int2(outStart + lrs, outStart + lrs + myDeg);
        dinv[n0 + tid] = rsqrtf((float)myDeg + 1.0f);
    }
    cur[tid] = lrs;
    // pad only this node's tail gap [lrs+deg, lrs+pdeg)
    for (int p = lrs + myDeg; p < lrs + pdeg; ++p) colbuf[p] = N_NODES;
    __syncthreads();
    for (int i = tid; i < runLen; i += 256) {
        unsigned e = staging[runStart + i];
        int p = atomicAdd(&cur[e >> 20], 1);
        if (p < CAPP) colbuf[p] = (int)(e & 0xFFFFF);
    }
    __syncthreads();
    int ptot = min(wsum[0] + wsum[1] + wsum[2] + wsum[3], CAPP);
    for (int i = tid; i < ptot; i += 256) colidx[outStart + i] = colbuf[i];
    if (b == 0) {
        if (tid < 64) {            // zero pad row N_NODES in both feature buffers
            padA[(size_t)N_NODES * 64 + tid] = 0u;
            padB[(size_t)N_NODES * 64 + tid] = 0u;
        }
        if (tid == 0) dinv[N_NODES] = 0.f;   // pad-col weight
    }
}

// ------- aggregation: 1 node/wave, branch-free 16-edge chunks (proven optimum) ----
template <int MODE>
__global__ __launch_bounds__(256) void k_agg(const uint4* __restrict__ xsA,
                                             const uint4* __restrict__ xsB,
                                             const int2* __restrict__ rse,
                                             const float* __restrict__ dinv,
                                             unsigned* __restrict__ out,
                                             const int* __restrict__ col,
                                             const int* __restrict__ flags) {
    int lane = threadIdx.x & 63;
    int node = blockIdx.x * 4 + (threadIdx.x >> 6);
    int glane = lane & 15, grp = lane >> 4;
    const uint4* xs = (MODE == 0) ? (flags[0] ? xsB : xsA) : xsA;
    int2 rr = rse[node];
    int rs = rr.x, deg = rr.y - rr.x;
    int pend = rs + ((deg + 15) & ~15);
    f2v a0 = {0.f, 0.f}, a1 = {0.f, 0.f}, a2 = {0.f, 0.f}, a3 = {0.f, 0.f};
    uint4 selfu = make_uint4(0u, 0u, 0u, 0u);
    float di = 0.f;
    if (MODE == 0) {
        selfu = xs[(unsigned)node * 16u + glane];
        di = dinv[node];
    }

    for (int base = rs; base < pend; base += 16) {
        int4 c = *(const int4*)(col + base + grp * 4);
        float dv0, dv1, dv2, dv3;
        if (MODE == 0) {
            dv0 = dinv[c.x]; dv1 = dinv[c.y]; dv2 = dinv[c.z]; dv3 = dinv[c.w];
            c.x = min(c.x, N_NODES - 1); c.y = min(c.y, N_NODES - 1);
            c.z = min(c.z, N_NODES - 1); c.w = min(c.w, N_NODES - 1);
        }
        uint4 u0 = xs[(unsigned)c.x * 16u + glane];
        uint4 u1 = xs[(unsigned)c.y * 16u + glane];
        uint4 u2 = xs[(unsigned)c.z * 16u + glane];
        uint4 u3 = xs[(unsigned)c.w * 16u + glane];
        if (MODE == 0) {
            a0 += dv0 * up2(u0.x); a1 += dv0 * up2(u0.y); a2 += dv0 * up2(u0.z); a3 += dv0 * up2(u0.w);
            a0 += dv1 * up2(u1.x); a1 += dv1 * up2(u1.y); a2 += dv1 * up2(u1.z); a3 += dv1 * up2(u1.w);
            a0 += dv2 * up2(u2.x); a1 += dv2 * up2(u2.y); a2 += dv2 * up2(u2.z); a3 += dv2 * up2(u2.w);
            a0 += dv3 * up2(u3.x); a1 += dv3 * up2(u3.y); a2 += dv3 * up2(u3.z); a3 += dv3 * up2(u3.w);
        } else {
            a0 += up2(u0.x); a1 += up2(u0.y); a2 += up2(u0.z); a3 += up2(u0.w);
            a0 += up2(u1.x); a1 += up2(u1.y); a2 += up2(u1.z); a3 += up2(u1.w);
            a0 += up2(u2.x); a1 += up2(u2.y); a2 += up2(u2.z); a3 += up2(u2.w);
            a0 += up2(u3.x); a1 += up2(u3.y); a2 += up2(u3.z); a3 += up2(u3.w);
        }
    }
    float r[8] = {a0.x, a0.y, a1.x, a1.y, a2.x, a2.y, a3.x, a3.y};
    #pragma unroll
    for (int i = 0; i < 8; ++i) {
        float v = r[i];
        v += __shfl_xor(v, 16, 64);
        v += __shfl_xor(v, 32, 64);
        r[i] = v;
    }
    if (MODE == 0) {
        float d2 = di * di;
        r[0] = di * r[0] + d2 * bflo(selfu.x); r[1] = di * r[1] + d2 * bfhi(selfu.x);
        r[2] = di * r[2] + d2 * bflo(selfu.y); r[3] = di * r[3] + d2 * bfhi(selfu.y);
        r[4] = di * r[4] + d2 * bflo(selfu.z); r[5] = di * r[5] + d2 * bfhi(selfu.z);
        r[6] = di * r[6] + d2 * bflo(selfu.w); r[7] = di * r[7] + d2 * bfhi(selfu.w);
    } else {
        float s = 1.0f / fmaxf((float)deg, 1.0f);
        #pragma unroll
        for (int i = 0; i < 8; ++i) r[i] *= s;
    }
    if (grp == 0) {
        uint4 o;
        o.x = pk(r[0], r[1]); o.y = pk(r[2], r[3]);
        o.z = pk(r[4], r[5]); o.w = pk(r[6], r[7]);
        *(uint4*)(out + (size_t)node * 64 + glane * 4) = o;
    }
}

// ------- MFMA GEMM: direct-A fragments from global, only W in LDS ----------------
// POOL=1 (SAGE2): skip the output write; global-mean-pool partial sums into pgsum
// via per-block LDS segment reduction (rows are graph-sorted; block spans <=2
// graphs normally; s>=4 overflow falls back to direct atomics).
template <int DUAL, int POOL>
__global__ __launch_bounds__(512) void k_gemm(const unsigned short* __restrict__ A0,
                                              const void* __restrict__ W0,
                                              const unsigned short* __restrict__ A1,
                                              const void* __restrict__ W1,
                                              const void* __restrict__ bias,
                                              unsigned short* __restrict__ out,
                                              const int* __restrict__ flags,
                                              const int* __restrict__ gstart,
                                              float* __restrict__ pgsum) {
    __shared__ __align__(16) unsigned short Ws[128][136];
    int f32 = flags[0];
    int tid = threadIdx.x;
    int lane = tid & 63;
    int wave = tid >> 6;
    int rowbase = blockIdx.x * 128;
    int lr = lane & 15, q = lane >> 4;
    int m0 = wave * 16;
    int arow = rowbase + m0 + lr;
    if (arow > N_NODES) arow = N_NODES;    // clamp into zero pad row

    f4v acc[8];
    #pragma unroll
    for (int t = 0; t < 8; ++t) acc[t] = (f4v){0.f, 0.f, 0.f, 0.f};

    #pragma unroll
    for (int p = 0; p < (DUAL ? 2 : 1); ++p) {
        const unsigned short* Ap = p ? A1 : A0;
        const void* Wp = p ? W1 : W0;
        if (p) __syncthreads();     // all waves done reading Ws of p=0
        if (!f32) {
            const unsigned short* Wf = (const unsigned short*)Wp;
            #pragma unroll
            for (int it = 0; it < 4; ++it) {
                int chunk = tid + it * 512;
                int r = chunk >> 4, c8 = (chunk & 15) * 8;
                *(uint4*)&Ws[r][c8] = *(const uint4*)(Wf + r * 128 + c8);
            }
        } else {
            const float* Wf = (const float*)Wp;
            #pragma unroll
            for (int it = 0; it < 8; ++it) {
                int chunk = tid + it * 512;
                int r = chunk >> 5, c4 = (chunk & 31) * 4;
                float4 v = *(const float4*)(Wf + r * 128 + c4);
                *(uint2*)&Ws[r][c4] = make_uint2(pk(v.x, v.y), pk(v.z, v.w));
            }
        }
        // A fragments: direct global loads (issued before the barrier to overlap)
        const unsigned short* Arp = Ap + (size_t)arow * 128;
        s8v a[4];
        #pragma unroll
        for (int k = 0; k < 4; ++k) a[k] = *(const s8v*)(Arp + k * 32 + q * 8);
        __syncthreads();
        #pragma unroll
        for (int k = 0; k < 4; ++k) {
            #pragma unroll
            for (int t = 0; t < 8; ++t) {
                s8v b = *(const s8v*)&Ws[t * 16 + lr][k * 32 + q * 8];
                acc[t] = __builtin_amdgcn_mfma_f32_16x16x32_bf16(a[k], b, acc[t], 0, 0, 0);
            }
        }
    }
    if (!POOL) {
        // epilogue: bias + store
        #pragma unroll
        for (int t = 0; t < 8; ++t) {
            int o = t * 16 + lr;
            float bv = ldv(bias, o, f32);
            #pragma unroll
            for (int j = 0; j < 4; ++j) {
                int m = rowbase + m0 + q * 4 + j;
                if (m < N_NODES) out[(size_t)m * 128 + o] = f2bf(acc[t][j] + bv);
            }
        }
    } else {
        // fused global-mean-pool epilogue (output tensor never written)
        float* segf = (float*)&Ws[0][0];       // 4 x 128 f32 segment sums
        __syncthreads();                       // all Ws MFMA reads done
        segf[tid] = 0.f;                       // 512 threads = 4*128 slots
        __syncthreads();
        // graph of block start (uniform across block)
        int gLo;
        {
            int lo = 0, hi = NGRAPH - 1;
            while (lo < hi) { int mid = (lo + hi + 1) >> 1; if (gstart[mid] <= rowbase) lo = mid; else hi = mid - 1; }
            gLo = lo;
        }
        int g = gLo;
        #pragma unroll
        for (int j = 0; j < 4; ++j) {
            int m = rowbase + m0 + q * 4 + j;
            if (m < N_NODES) {
                while (gstart[g + 1] <= m) ++g;   // gstart[64]=N_NODES terminates
                int s = g - gLo;
                #pragma unroll
                for (int t = 0; t < 8; ++t) {
                    int o = t * 16 + lr;
                    float val = acc[t][j] + ldv(bias, o, f32);
                    if (s < 4) atomicAdd(&segf[s * 128 + o], val);
                    else atomicAdd(&pgsum[g * 128 + o], val);   // pathological fallback
                }
            }
        }
        __syncthreads();
        // flush segments (skip zero partials)
        int s = tid >> 7, o = tid & 127;
        int g2 = gLo + s;
        if (g2 < NGRAPH) {
            float vv = segf[tid];
            if (vv != 0.f) atomicAdd(&pgsum[g2 * 128 + o], vv);
        }
    }
}

// ---------------- fused classifier: pool-finalize + 4 layers + softmax ----------
__global__ __launch_bounds__(256) void k_clf(const float* __restrict__ pgsum,
                                             const int* __restrict__ gstart,
                                             const float* __restrict__ wbuf,
                                             const float* __restrict__ pbuf,
                                             void* outv, const int* __restrict__ flags) {
    __shared__ float gin[128];
    __shared__ float ha[200];
    __shared__ float hb[100];
    int b = blockIdx.x, t = threadIdx.x;
    if (t < 128) {
        int cnt = gstart[b + 1] - gstart[b];
        gin[t] = pgsum[b * 128 + t] / fmaxf((float)cnt, 1.0f);
    }
    __syncthreads();
    if (t < 200) {
        const float4* wr = (const float4*)(wbuf + t * 128);
        float s = 0.f;
        #pragma unroll
        for (int k = 0; k < 32; ++k) {
            float4 v = wr[k];
            s += v.x * gin[4 * k] + v.y * gin[4 * k + 1] + v.z * gin[4 * k + 2] + v.w * gin[4 * k + 3];
        }
        ha[t] = tanhf(s * pbuf[t] + pbuf[200 + t]);
    }
    __syncthreads();
    if (t < 100) {
        const float4* wr = (const float4*)(wbuf + 25600 + t * 200);
        float s = 0.f;
        #pragma unroll
        for (int k = 0; k < 50; ++k) {
            float4 v = wr[k];
            s += v.x * ha[4 * k] + v.y * ha[4 * k + 1] + v.z * ha[4 * k + 2] + v.w * ha[4 * k + 3];
        }
        hb[t] = tanhf(s * pbuf[400 + t] + pbuf[500 + t]);
    }
    __syncthreads();
    if (t < 50) {
        const float4* wr = (const float4*)(wbuf + 45600 + t * 100);
        float s = 0.f;
        #pragma unroll
        for (int k = 0; k < 25; ++k) {
            float4 v = wr[k];
            s += v.x * hb[4 * k] + v.y * hb[4 * k + 1] + v.z * hb[4 * k + 2] + v.w * hb[4 * k + 3];
        }
        gin[t] = tanhf(s * pbuf[600 + t] + pbuf[650 + t]);
    }
    __syncthreads();
    if (t == 0) {
        int f = flags[0];
        float lg[10];
        float mx = -1e30f;
        #pragma unroll
        for (int c = 0; c < 10; ++c) {
            const float* wr = wbuf + 50600 + c * 50;
            float s = 0.f;
            for (int k = 0; k < 50; ++k) s += wr[k] * gin[k];
            s += pbuf[700 + c];
            lg[c] = s;
            mx = fmaxf(mx, s);
        }
        float sum = 0.f;
        #pragma unroll
        for (int c = 0; c < 10; ++c) {
            lg[c] = __expf(lg[c] - mx);
            sum += lg[c];
        }
        float inv = 1.0f / sum;
        #pragma unroll
        for (int c = 0; c < 10; ++c) {
            float v = lg[c] * inv;
            if (f) ((float*)outv)[b * 10 + c] = v;
            else ((unsigned short*)outv)[b * 10 + c] = f2bf(v);
        }
    }
}

extern "C" void kernel_launch(void* const* d_in, const int* in_sizes, int n_in,
                              void* d_out, int out_size, void* d_ws, size_t ws_size,
                              hipStream_t stream) {
    const unsigned short* x16 = (const unsigned short*)d_in[0];
    const int* ei = (const int*)d_in[1];
    const int* batch = (const int*)d_in[2];

    char* ws = (char*)d_ws;
    size_t off = 0;
    auto alloc = [&](size_t bytes) {
        size_t r = off;
        off = (off + bytes + 255) & ~(size_t)255;
        return r;
    };
    int* flags = (int*)(ws + alloc(256));
    int2* rse = (int2*)(ws + alloc((size_t)N_NODES * 8));
    int* colidx = (int*)(ws + alloc((size_t)NBIN * CAPP * 4 + (size_t)CAPP * 4));
    float* dinv = (float*)(ws + alloc((size_t)(N_NODES + 1) * 4));
    int* binCur = (int*)(ws + alloc(NBIN * 4));
    int* gstart = (int*)(ws + alloc((NGRAPH + 1) * 4));
    float* pbuf = (float*)(ws + alloc(710 * 4));
    float* pgsum = (float*)(ws + alloc((size_t)NGRAPH * 128 * 4));
    float* wbuf = (float*)(ws + alloc(51100 * 4));
    // +1 pad row (index N_NODES, kept zero) in both feature buffers
    unsigned short* bufA = (unsigned short*)(ws + alloc((size_t)(N_NODES + 1) * 128 * 2));
    unsigned short* bufB = (unsigned short*)(ws + alloc((size_t)(N_NODES + 1) * 128 * 2));
    unsigned* staging = (unsigned*)bufA;  // 391*6144*4 = 9.6 MB < 25.6 MB; consumed in k_csr
                                          // before anything writes bufA (pad row @25.6MB is past it)

    k_setup<<<SETUPBLK, 256, 0, stream>>>(x16, ei, batch, flags, binCur, gstart, pbuf, wbuf,
                                          (unsigned*)bufB, pgsum,
                                          d_in[11], d_in[13], d_in[15], d_in[17],
                                          d_in[12], d_in[19], d_in[20],
                                          d_in[14], d_in[21], d_in[22],
                                          d_in[16], d_in[23], d_in[24], d_in[18]);

    // lean padded-bin CSR build (+ pad-row zeroing in k_csr block 0)
    k_binfill<<<NBLK, 256, 0, stream>>>(ei, binCur, staging, flags);
    k_csr<<<NBIN, 256, 0, stream>>>(staging, binCur, rse, dinv, colidx,
                                    (unsigned*)bufA, (unsigned*)bufB);

    // GCN: gather x directly with dinv fma -> bufA; gemm (direct-A) in-place
    k_agg<0><<<N_NODES / 4, 256, 0, stream>>>((const uint4*)x16, (const uint4*)bufB,
                                              rse, dinv, (unsigned*)bufA, colidx, flags);
    k_gemm<0, 0><<<(N_NODES + 127) / 128, 512, 0, stream>>>(bufA, d_in[3], nullptr, nullptr,
                                                            d_in[4], bufA, flags, gstart, pgsum);
    // SAGE1
    k_agg<1><<<N_NODES / 4, 256, 0, stream>>>((const uint4*)bufA, (const uint4*)bufA,
                                              rse, dinv, (unsigned*)bufB, colidx, flags);
    k_gemm<1, 0><<<(N_NODES + 127) / 128, 512, 0, stream>>>(bufB, d_in[5], bufA, d_in[7],
                                                            d_in[6], bufB, flags, gstart, pgsum);
    // SAGE2: agg bufB -> bufA; gemm with FUSED POOL (no output write)
    k_agg<1><<<N_NODES / 4, 256, 0, stream>>>((const uint4*)bufB, (const uint4*)bufB,
                                              rse, dinv, (unsigned*)bufA, colidx, flags);
    k_gemm<1, 1><<<(N_NODES + 127) / 128, 512, 0, stream>>>(bufA, d_in[8], bufB, d_in[10],
                                                            d_in[9], bufA, flags, gstart, pgsum);
    // fused classifier (reads pgsum directly)
    k_clf<<<NGRAPH, 256, 0, stream>>>(pgsum, gstart, wbuf, pbuf, d_out, flags);
}

// Round 10
// 450.575 us; speedup vs baseline: 1.1642x; 1.1642x over previous
//
#include <hip/hip_runtime.h>

#define N_NODES 100000
#define N_EDGES 1600000
#define NGRAPH 64
#define NBIN 391        // ceil(100000/256) bins of 256 nodes (dst>>8)
#define EPB 2560        // edges per binning block (multiple of 512)
#define NBLK 625        // 625*2560 = 1.6M
#define CAPB 6144       // staging per-bin capacity (unpadded; avg 4092, +32 sigma)
#define CAPP 7168       // padded colidx per-bin stride (avg 6144 w/ pad-16, ~+8 sigma)
#define SETUPBLK 1600   // k_setup grid (covers wbuf 51100 and x-convert stride)

typedef short s8v __attribute__((ext_vector_type(8)));
typedef float f4v __attribute__((ext_vector_type(4)));
typedef float f2v __attribute__((ext_vector_type(2)));

__device__ __forceinline__ float bflo(unsigned u) { return __uint_as_float(u << 16); }
__device__ __forceinline__ float bfhi(unsigned u) { return __uint_as_float(u & 0xffff0000u); }
__device__ __forceinline__ unsigned short f2bf(float f) {
    unsigned u = __float_as_uint(f);
    u += 0x7fffu + ((u >> 16) & 1u);
    return (unsigned short)(u >> 16);
}
__device__ __forceinline__ float bf2f(unsigned short h) { return __uint_as_float(((unsigned)h) << 16); }
__device__ __forceinline__ unsigned pk(float lo, float hi) {
    return (unsigned)f2bf(lo) | ((unsigned)f2bf(hi) << 16);
}
__device__ __forceinline__ float ldv(const void* p, int i, int f32) {
    return f32 ? ((const float*)p)[i] : bf2f(((const unsigned short*)p)[i]);
}
__device__ __forceinline__ f2v up2(unsigned u) {
    f2v t; t.x = bflo(u); t.y = bfhi(u); return t;
}
__device__ __forceinline__ int graph_of(const int* __restrict__ gstart, int m) {
    int lo = 0, hi = NGRAPH - 1;
    while (lo < hi) {
        int mid = (lo + hi + 1) >> 1;
        if (gstart[mid] <= m) lo = mid;
        else hi = mid - 1;
    }
    return lo;
}

// ------- setup + cvt_w + x-convert merged: every block detects dtype locally ------
__global__ __launch_bounds__(256) void k_setup(const unsigned short* __restrict__ x,
                                               const int* __restrict__ ei,
                                               const int* __restrict__ batch,
                                               int* __restrict__ flags,
                                               int* __restrict__ binCur,
                                               int* __restrict__ gstart,
                                               float* __restrict__ pbuf,
                                               float* __restrict__ wbuf,
                                               unsigned* __restrict__ xcvt,
                                               float* __restrict__ pgsum,
                                               const void* w0, const void* w1,
                                               const void* w2, const void* w3,
                                               const void* b0, const void* bn0g, const void* bn0b,
                                               const void* b1, const void* bn1g, const void* bn1b,
                                               const void* b2, const void* bn2g, const void* bn2b,
                                               const void* b3) {
    __shared__ int cnt[3];
    int tid = threadIdx.x, bid = blockIdx.x;
    if (tid < 3) cnt[tid] = 0;
    __syncthreads();
    unsigned short h = x[tid * 37];
    int e = (h >> 7) & 0xFF;
    if (e >= 100 && e <= 150) atomicAdd(&cnt[0], 1);
    if (bid == 0) {
        if (ei[2 * (tid * 5000) + 1] == 0) atomicAdd(&cnt[1], 1);
        if (batch[2 * (tid * 193) + 1] == 0) atomicAdd(&cnt[2], 1);
    }
    __syncthreads();
    int f = (cnt[0] == 256) ? 0 : 1;
    // weight conversion slice (blocks 0..199)
    int i = bid * 256 + tid;
    if (i < 25600) wbuf[i] = ldv(w0, i, f);
    else if (i < 45600) wbuf[i] = ldv(w1, i - 25600, f);
    else if (i < 50600) wbuf[i] = ldv(w2, i - 45600, f);
    else if (i < 51100) wbuf[i] = ldv(w3, i - 50600, f);
    // f32 inputs: convert x -> xcvt (bf16), grid-stride
    if (f) {
        for (int id = bid * 256 + tid; id < N_NODES * 64; id += SETUPBLK * 256) {
            float2 u = ((const float2*)x)[id];
            xcvt[id] = pk(u.x, u.y);
        }
    }
    if (bid != 0) return;
    int b64 = (cnt[2] == 256) ? 1 : 0;
    if (tid == 0) {
        flags[0] = f;
        flags[1] = (cnt[1] == 256) ? 1 : 0;
        flags[2] = b64;
    }
    for (int k = tid; k < NBIN; k += 256) binCur[k] = 0;
    for (int k = tid; k < NGRAPH * 128; k += 256) pgsum[k] = 0.f;
    if (tid <= NGRAPH) {
        int g = tid, lo = 0, hi = N_NODES;
        while (lo < hi) {
            int mid = (lo + hi) >> 1;
            int v = b64 ? batch[2 * mid] : batch[mid];
            if (v < g) lo = mid + 1;
            else hi = mid;
        }
        gstart[g] = lo;
    }
    const float invs = rsqrtf(1.0f + 1e-5f);
    if (tid < 200) {
        float a = ldv(bn0g, tid, f) * invs;
        pbuf[tid] = a;
        pbuf[200 + tid] = ldv(b0, tid, f) * a + ldv(bn0b, tid, f);
    }
    if (tid < 100) {
        float a = ldv(bn1g, tid, f) * invs;
        pbuf[400 + tid] = a;
        pbuf[500 + tid] = ldv(b1, tid, f) * a + ldv(bn1b, tid, f);
    }
    if (tid < 50) {
        float a = ldv(bn2g, tid, f) * invs;
        pbuf[600 + tid] = a;
        pbuf[650 + tid] = ldv(b2, tid, f) * a + ldv(bn2b, tid, f);
    }
    if (tid < 10) pbuf[700 + tid] = ldv(b3, tid, f);
}

// ---------------- LEAN binfill: histogram -> reserve -> direct scatter ----------
__global__ __launch_bounds__(256) void k_binfill(const int* __restrict__ ei,
                                                 int* __restrict__ binCur,
                                                 unsigned* __restrict__ staging,
                                                 const int* __restrict__ flags) {
    __shared__ int cnt[NBIN];
    __shared__ int basg[NBIN];
    __shared__ int dbuf[EPB];
    int tid = threadIdx.x;
    int i64 = flags[1];
    int base = blockIdx.x * EPB;
    for (int i = tid; i < NBIN; i += 256) cnt[i] = 0;
    __syncthreads();
    // pass 1: dst (cached in LDS), histogram
    #pragma unroll
    for (int k = 0; k < EPB / 512; ++k) {
        int e = base + k * 512 + tid * 2;
        int d0, d1;
        if (i64) {
            uint4 vd = *(const uint4*)(ei + 2 * (size_t)(N_EDGES + e));
            d0 = (int)vd.x; d1 = (int)vd.z;
        } else {
            int2 vd = *(const int2*)(ei + (size_t)N_EDGES + e);
            d0 = vd.x; d1 = vd.y;
        }
        int l = k * 512 + tid * 2;
        dbuf[l] = d0; dbuf[l + 1] = d1;
        if ((unsigned)d0 < N_NODES) atomicAdd(&cnt[d0 >> 8], 1);
        if ((unsigned)d1 < N_NODES) atomicAdd(&cnt[d1 >> 8], 1);
    }
    __syncthreads();
    // reserve a contiguous run per bin; reuse cnt as scatter cursor
    for (int i = tid; i < NBIN; i += 256) {
        int c = cnt[i];
        basg[i] = i * CAPB + (c ? atomicAdd(&binCur[i], c) : 0);
        cnt[i] = 0;
    }
    __syncthreads();
    // pass 2: src from global (L2-hot lines), direct scatter into reserved runs
    #pragma unroll
    for (int k = 0; k < EPB / 512; ++k) {
        int e = base + k * 512 + tid * 2;
        int s0, s1;
        if (i64) {
            uint4 vs = *(const uint4*)(ei + 2 * (size_t)e);
            s0 = (int)vs.x; s1 = (int)vs.z;
        } else {
            int2 vs = *(const int2*)(ei + (size_t)e);
            s0 = vs.x; s1 = vs.y;
        }
        int l = k * 512 + tid * 2;
        #pragma unroll
        for (int hh = 0; hh < 2; ++hh) {
            int d = dbuf[l + hh];
            int s = hh ? s1 : s0;
            if ((unsigned)d < N_NODES) {
                s = min(max(s, 0), N_NODES - 1);
                int b = d >> 8;
                int p = atomicAdd(&cnt[b], 1);
                int pos = basg[b] + p;
                if (pos < (b + 1) * CAPB)
                    staging[pos] = ((unsigned)(d & 255) << 20) | (unsigned)s;
            }
        }
    }
}

// per-bin sub-CSR -> rse(int2) + dinv + PADDED colidx (pad idx = N_NODES).
// shfl-scan (1 barrier) + gap-only pad init. Block 0 zeroes pad rows + dinv[N].
__global__ __launch_bounds__(256) void k_csr(const unsigned* __restrict__ staging,
                                             const int* __restrict__ binCur,
                                             int2* __restrict__ rse,
                                             float* __restrict__ dinv,
                                             int* __restrict__ colidx,
                                             unsigned* __restrict__ padA,
                                             unsigned* __restrict__ padB) {
    __shared__ int deg[256];
    __shared__ int cur[256];
    __shared__ int wsum[4];
    __shared__ int colbuf[CAPP];
    int b = blockIdx.x, tid = threadIdx.x;
    int lane = tid & 63, wv = tid >> 6;
    int n0 = b << 8;
    int nend = min(256, N_NODES - n0);
    int runStart = b * CAPB;
    int outStart = b * CAPP;
    int runLen = min(binCur[b], CAPB);
    deg[tid] = 0;
    __syncthreads();
    for (int i = tid; i < runLen; i += 256)
        atomicAdd(&deg[staging[runStart + i] >> 20], 1);
    __syncthreads();
    int myDeg = deg[tid];
    int pdeg = (myDeg + 15) & ~15;   // pad each node's list to x16
    // per-wave inclusive shfl scan of pdeg, then cross-wave prefix
    int v = pdeg;
    #pragma unroll
    for (int off = 1; off < 64; off <<= 1) {
        int n = __shfl_up(v, off, 64);
        if (lane >= off) v += n;
    }
    if (lane == 63) wsum[wv] = v;
    __syncthreads();
    int prefix = 0;
    #pragma unroll
    for (int w = 0; w < 4; ++w) prefix += (w < wv) ? wsum[w] : 0;
    int incl = v + prefix;
    int lrs = incl - pdeg;
    if (tid < nend) {
        rse[n0 + tid] = make_int2(outStart + lrs, outStart + lrs + myDeg);
        dinv[n0 + tid] = rsqrtf((float)myDeg + 1.0f);
    }
    cur[tid] = lrs;
    // pad only this node's tail gap [lrs+deg, lrs+pdeg)
    for (int p = lrs + myDeg; p < lrs + pdeg; ++p) colbuf[p] = N_NODES;
    __syncthreads();
    for (int i = tid; i < runLen; i += 256) {
        unsigned e = staging[runStart + i];
        int p = atomicAdd(&cur[e >> 20], 1);
        if (p < CAPP) colbuf[p] = (int)(e & 0xFFFFF);
    }
    __syncthreads();
    int ptot = min(wsum[0] + wsum[1] + wsum[2] + wsum[3], CAPP);
    for (int i = tid; i < ptot; i += 256) colidx[outStart + i] = colbuf[i];
    if (b == 0) {
        if (tid < 64) {            // zero pad row N_NODES in both feature buffers
            padA[(size_t)N_NODES * 64 + tid] = 0u;
            padB[(size_t)N_NODES * 64 + tid] = 0u;
        }
        if (tid == 0) dinv[N_NODES] = 0.f;   // pad-col weight
    }
}

// ------- aggregation: 1 node/wave, branch-free 16-edge chunks (proven optimum) ----
template <int MODE>
__global__ __launch_bounds__(256) void k_agg(const uint4* __restrict__ xsA,
                                             const uint4* __restrict__ xsB,
                                             const int2* __restrict__ rse,
                                             const float* __restrict__ dinv,
                                             unsigned* __restrict__ out,
                                             const int* __restrict__ col,
                                             const int* __restrict__ flags) {
    int lane = threadIdx.x & 63;
    int node = blockIdx.x * 4 + (threadIdx.x >> 6);
    int glane = lane & 15, grp = lane >> 4;
    const uint4* xs = (MODE == 0) ? (flags[0] ? xsB : xsA) : xsA;
    int2 rr = rse[node];
    int rs = rr.x, deg = rr.y - rr.x;
    int pend = rs + ((deg + 15) & ~15);
    f2v a0 = {0.f, 0.f}, a1 = {0.f, 0.f}, a2 = {0.f, 0.f}, a3 = {0.f, 0.f};
    uint4 selfu = make_uint4(0u, 0u, 0u, 0u);
    float di = 0.f;
    if (MODE == 0) {
        selfu = xs[(unsigned)node * 16u + glane];
        di = dinv[node];
    }

    for (int base = rs; base < pend; base += 16) {
        int4 c = *(const int4*)(col + base + grp * 4);
        float dv0, dv1, dv2, dv3;
        if (MODE == 0) {
            dv0 = dinv[c.x]; dv1 = dinv[c.y]; dv2 = dinv[c.z]; dv3 = dinv[c.w];
            c.x = min(c.x, N_NODES - 1); c.y = min(c.y, N_NODES - 1);
            c.z = min(c.z, N_NODES - 1); c.w = min(c.w, N_NODES - 1);
        }
        uint4 u0 = xs[(unsigned)c.x * 16u + glane];
        uint4 u1 = xs[(unsigned)c.y * 16u + glane];
        uint4 u2 = xs[(unsigned)c.z * 16u + glane];
        uint4 u3 = xs[(unsigned)c.w * 16u + glane];
        if (MODE == 0) {
            a0 += dv0 * up2(u0.x); a1 += dv0 * up2(u0.y); a2 += dv0 * up2(u0.z); a3 += dv0 * up2(u0.w);
            a0 += dv1 * up2(u1.x); a1 += dv1 * up2(u1.y); a2 += dv1 * up2(u1.z); a3 += dv1 * up2(u1.w);
            a0 += dv2 * up2(u2.x); a1 += dv2 * up2(u2.y); a2 += dv2 * up2(u2.z); a3 += dv2 * up2(u2.w);
            a0 += dv3 * up2(u3.x); a1 += dv3 * up2(u3.y); a2 += dv3 * up2(u3.z); a3 += dv3 * up2(u3.w);
        } else {
            a0 += up2(u0.x); a1 += up2(u0.y); a2 += up2(u0.z); a3 += up2(u0.w);
            a0 += up2(u1.x); a1 += up2(u1.y); a2 += up2(u1.z); a3 += up2(u1.w);
            a0 += up2(u2.x); a1 += up2(u2.y); a2 += up2(u2.z); a3 += up2(u2.w);
            a0 += up2(u3.x); a1 += up2(u3.y); a2 += up2(u3.z); a3 += up2(u3.w);
        }
    }
    float r[8] = {a0.x, a0.y, a1.x, a1.y, a2.x, a2.y, a3.x, a3.y};
    #pragma unroll
    for (int i = 0; i < 8; ++i) {
        float v = r[i];
        v += __shfl_xor(v, 16, 64);
        v += __shfl_xor(v, 32, 64);
        r[i] = v;
    }
    if (MODE == 0) {
        float d2 = di * di;
        r[0] = di * r[0] + d2 * bflo(selfu.x); r[1] = di * r[1] + d2 * bfhi(selfu.x);
        r[2] = di * r[2] + d2 * bflo(selfu.y); r[3] = di * r[3] + d2 * bfhi(selfu.y);
        r[4] = di * r[4] + d2 * bflo(selfu.z); r[5] = di * r[5] + d2 * bfhi(selfu.z);
        r[6] = di * r[6] + d2 * bflo(selfu.w); r[7] = di * r[7] + d2 * bfhi(selfu.w);
    } else {
        float s = 1.0f / fmaxf((float)deg, 1.0f);
        #pragma unroll
        for (int i = 0; i < 8; ++i) r[i] *= s;
    }
    if (grp == 0) {
        uint4 o;
        o.x = pk(r[0], r[1]); o.y = pk(r[2], r[3]);
        o.z = pk(r[4], r[5]); o.w = pk(r[6], r[7]);
        *(uint4*)(out + (size_t)node * 64 + glane * 4) = o;
    }
}

// ------- MFMA GEMM: direct-A fragments from global, only W in LDS ----------------
// POOL=1 (SAGE2): no output write; pool via in-register shuffle reduce (a wave
// holds a full 16x128 tile) + one global atomic per (t, lane<16). Bias is NOT
// added here (k_clf adds it once per graph: mean(acc+b) = sum(acc)/cnt + b).
template <int DUAL, int POOL>
__global__ __launch_bounds__(512) void k_gemm(const unsigned short* __restrict__ A0,
                                              const void* __restrict__ W0,
                                              const unsigned short* __restrict__ A1,
                                              const void* __restrict__ W1,
                                              const void* __restrict__ bias,
                                              unsigned short* __restrict__ out,
                                              const int* __restrict__ flags,
                                              const int* __restrict__ gstart,
                                              float* __restrict__ pgsum) {
    __shared__ __align__(16) unsigned short Ws[128][136];
    int f32 = flags[0];
    int tid = threadIdx.x;
    int lane = tid & 63;
    int wave = tid >> 6;
    int rowbase = blockIdx.x * 128;
    int lr = lane & 15, q = lane >> 4;
    int m0 = wave * 16;
    int arow = rowbase + m0 + lr;
    if (arow > N_NODES) arow = N_NODES;    // clamp into zero pad row

    f4v acc[8];
    #pragma unroll
    for (int t = 0; t < 8; ++t) acc[t] = (f4v){0.f, 0.f, 0.f, 0.f};

    #pragma unroll
    for (int p = 0; p < (DUAL ? 2 : 1); ++p) {
        const unsigned short* Ap = p ? A1 : A0;
        const void* Wp = p ? W1 : W0;
        if (p) __syncthreads();     // all waves done reading Ws of p=0
        if (!f32) {
            const unsigned short* Wf = (const unsigned short*)Wp;
            #pragma unroll
            for (int it = 0; it < 4; ++it) {
                int chunk = tid + it * 512;
                int r = chunk >> 4, c8 = (chunk & 15) * 8;
                *(uint4*)&Ws[r][c8] = *(const uint4*)(Wf + r * 128 + c8);
            }
        } else {
            const float* Wf = (const float*)Wp;
            #pragma unroll
            for (int it = 0; it < 8; ++it) {
                int chunk = tid + it * 512;
                int r = chunk >> 5, c4 = (chunk & 31) * 4;
                float4 v = *(const float4*)(Wf + r * 128 + c4);
                *(uint2*)&Ws[r][c4] = make_uint2(pk(v.x, v.y), pk(v.z, v.w));
            }
        }
        // A fragments: direct global loads (issued before the barrier to overlap)
        const unsigned short* Arp = Ap + (size_t)arow * 128;
        s8v a[4];
        #pragma unroll
        for (int k = 0; k < 4; ++k) a[k] = *(const s8v*)(Arp + k * 32 + q * 8);
        __syncthreads();
        #pragma unroll
        for (int k = 0; k < 4; ++k) {
            #pragma unroll
            for (int t = 0; t < 8; ++t) {
                s8v b = *(const s8v*)&Ws[t * 16 + lr][k * 32 + q * 8];
                acc[t] = __builtin_amdgcn_mfma_f32_16x16x32_bf16(a[k], b, acc[t], 0, 0, 0);
            }
        }
    }
    if (!POOL) {
        // epilogue: bias + store
        #pragma unroll
        for (int t = 0; t < 8; ++t) {
            int o = t * 16 + lr;
            float bv = ldv(bias, o, f32);
            #pragma unroll
            for (int j = 0; j < 4; ++j) {
                int m = rowbase + m0 + q * 4 + j;
                if (m < N_NODES) out[(size_t)m * 128 + o] = f2bf(acc[t][j] + bv);
            }
        }
    } else {
        // fused global-mean-pool epilogue, in-register (no LDS, no per-elem atomics)
        int rlo = rowbase + m0;                       // wave rows: rlo..rlo+15
        int rhi = min(rlo + 15, N_NODES - 1);
        int gLo = graph_of(gstart, min(rlo, N_NODES - 1));
        int gHi = graph_of(gstart, rhi);
        if (gLo == gHi) {
            // fast path: whole wave tile in one graph (pad rows contribute 0)
            #pragma unroll
            for (int t = 0; t < 8; ++t) {
                float v = acc[t][0] + acc[t][1] + acc[t][2] + acc[t][3];
                v += __shfl_xor(v, 16, 64);
                v += __shfl_xor(v, 32, 64);
                if (lane < 16) atomicAdd(&pgsum[gLo * 128 + t * 16 + lr], v);
            }
        } else {
            // crossing wave (rare): per-row atomics
            #pragma unroll
            for (int j = 0; j < 4; ++j) {
                int m = rowbase + m0 + q * 4 + j;
                if (m < N_NODES) {
                    int g = graph_of(gstart, m);
                    #pragma unroll
                    for (int t = 0; t < 8; ++t)
                        atomicAdd(&pgsum[g * 128 + t * 16 + lr], acc[t][j]);
                }
            }
        }
    }
}

// ---------------- fused classifier: pool-finalize + 4 layers + softmax ----------
__global__ __launch_bounds__(256) void k_clf(const float* __restrict__ pgsum,
                                             const int* __restrict__ gstart,
                                             const float* __restrict__ wbuf,
                                             const float* __restrict__ pbuf,
                                             const void* __restrict__ bias3,
                                             void* outv, const int* __restrict__ flags) {
    __shared__ float gin[128];
    __shared__ float ha[200];
    __shared__ float hb[100];
    int b = blockIdx.x, t = threadIdx.x;
    int f = flags[0];
    if (t < 128) {
        int cnt = gstart[b + 1] - gstart[b];
        gin[t] = pgsum[b * 128 + t] / fmaxf((float)cnt, 1.0f) + ldv(bias3, t, f);
    }
    __syncthreads();
    if (t < 200) {
        const float4* wr = (const float4*)(wbuf + t * 128);
        float s = 0.f;
        #pragma unroll
        for (int k = 0; k < 32; ++k) {
            float4 v = wr[k];
            s += v.x * gin[4 * k] + v.y * gin[4 * k + 1] + v.z * gin[4 * k + 2] + v.w * gin[4 * k + 3];
        }
        ha[t] = tanhf(s * pbuf[t] + pbuf[200 + t]);
    }
    __syncthreads();
    if (t < 100) {
        const float4* wr = (const float4*)(wbuf + 25600 + t * 200);
        float s = 0.f;
        #pragma unroll
        for (int k = 0; k < 50; ++k) {
            float4 v = wr[k];
            s += v.x * ha[4 * k] + v.y * ha[4 * k + 1] + v.z * ha[4 * k + 2] + v.w * ha[4 * k + 3];
        }
        hb[t] = tanhf(s * pbuf[400 + t] + pbuf[500 + t]);
    }
    __syncthreads();
    if (t < 50) {
        const float4* wr = (const float4*)(wbuf + 45600 + t * 100);
        float s = 0.f;
        #pragma unroll
        for (int k = 0; k < 25; ++k) {
            float4 v = wr[k];
            s += v.x * hb[4 * k] + v.y * hb[4 * k + 1] + v.z * hb[4 * k + 2] + v.w * hb[4 * k + 3];
        }
        gin[t] = tanhf(s * pbuf[600 + t] + pbuf[650 + t]);
    }
    __syncthreads();
    if (t == 0) {
        float lg[10];
        float mx = -1e30f;
        #pragma unroll
        for (int c = 0; c < 10; ++c) {
            const float* wr = wbuf + 50600 + c * 50;
            float s = 0.f;
            for (int k = 0; k < 50; ++k) s += wr[k] * gin[k];
            s += pbuf[700 + c];
            lg[c] = s;
            mx = fmaxf(mx, s);
        }
        float sum = 0.f;
        #pragma unroll
        for (int c = 0; c < 10; ++c) {
            lg[c] = __expf(lg[c] - mx);
            sum += lg[c];
        }
        float inv = 1.0f / sum;
        #pragma unroll
        for (int c = 0; c < 10; ++c) {
            float v = lg[c] * inv;
            if (f) ((float*)outv)[b * 10 + c] = v;
            else ((unsigned short*)outv)[b * 10 + c] = f2bf(v);
        }
    }
}

extern "C" void kernel_launch(void* const* d_in, const int* in_sizes, int n_in,
                              void* d_out, int out_size, void* d_ws, size_t ws_size,
                              hipStream_t stream) {
    const unsigned short* x16 = (const unsigned short*)d_in[0];
    const int* ei = (const int*)d_in[1];
    const int* batch = (const int*)d_in[2];

    char* ws = (char*)d_ws;
    size_t off = 0;
    auto alloc = [&](size_t bytes) {
        size_t r = off;
        off = (off + bytes + 255) & ~(size_t)255;
        return r;
    };
    int* flags = (int*)(ws + alloc(256));
    int2* rse = (int2*)(ws + alloc((size_t)N_NODES * 8));
    int* colidx = (int*)(ws + alloc((size_t)NBIN * CAPP * 4 + (size_t)CAPP * 4));
    float* dinv = (float*)(ws + alloc((size_t)(N_NODES + 1) * 4));
    int* binCur = (int*)(ws + alloc(NBIN * 4));
    int* gstart = (int*)(ws + alloc((NGRAPH + 1) * 4));
    float* pbuf = (float*)(ws + alloc(710 * 4));
    float* pgsum = (float*)(ws + alloc((size_t)NGRAPH * 128 * 4));
    float* wbuf = (float*)(ws + alloc(51100 * 4));
    // +1 pad row (index N_NODES, kept zero) in both feature buffers
    unsigned short* bufA = (unsigned short*)(ws + alloc((size_t)(N_NODES + 1) * 128 * 2));
    unsigned short* bufB = (unsigned short*)(ws + alloc((size_t)(N_NODES + 1) * 128 * 2));
    unsigned* staging = (unsigned*)bufA;  // 391*6144*4 = 9.6 MB < 25.6 MB; consumed in k_csr
                                          // before anything writes bufA (pad row @25.6MB is past it)

    k_setup<<<SETUPBLK, 256, 0, stream>>>(x16, ei, batch, flags, binCur, gstart, pbuf, wbuf,
                                          (unsigned*)bufB, pgsum,
                                          d_in[11], d_in[13], d_in[15], d_in[17],
                                          d_in[12], d_in[19], d_in[20],
                                          d_in[14], d_in[21], d_in[22],
                                          d_in[16], d_in[23], d_in[24], d_in[18]);

    // lean padded-bin CSR build (+ pad-row zeroing in k_csr block 0)
    k_binfill<<<NBLK, 256, 0, stream>>>(ei, binCur, staging, flags);
    k_csr<<<NBIN, 256, 0, stream>>>(staging, binCur, rse, dinv, colidx,
                                    (unsigned*)bufA, (unsigned*)bufB);

    // GCN: gather x directly with dinv fma -> bufA; gemm (direct-A) in-place
    k_agg<0><<<N_NODES / 4, 256, 0, stream>>>((const uint4*)x16, (const uint4*)bufB,
                                              rse, dinv, (unsigned*)bufA, colidx, flags);
    k_gemm<0, 0><<<(N_NODES + 127) / 128, 512, 0, stream>>>(bufA, d_in[3], nullptr, nullptr,
                                                            d_in[4], bufA, flags, gstart, pgsum);
    // SAGE1
    k_agg<1><<<N_NODES / 4, 256, 0, stream>>>((const uint4*)bufA, (const uint4*)bufA,
                                              rse, dinv, (unsigned*)bufB, colidx, flags);
    k_gemm<1, 0><<<(N_NODES + 127) / 128, 512, 0, stream>>>(bufB, d_in[5], bufA, d_in[7],
                                                            d_in[6], bufB, flags, gstart, pgsum);
    // SAGE2: agg bufB -> bufA; gemm with FUSED POOL (no output write, no bias)
    k_agg<1><<<N_NODES / 4, 256, 0, stream>>>((const uint4*)bufB, (const uint4*)bufB,
                                              rse, dinv, (unsigned*)bufA, colidx, flags);
    k_gemm<1, 1><<<(N_NODES + 127) / 128, 512, 0, stream>>>(bufA, d_in[8], bufB, d_in[10],
                                                            d_in[9], bufA, flags, gstart, pgsum);
    // fused classifier (reads pgsum; adds SAGE2 bias once per graph)
    k_clf<<<NGRAPH, 256, 0, stream>>>(pgsum, gstart, wbuf, pbuf, d_in[9], d_out, flags);
}